// Round 3
// baseline (399.098 us; speedup 1.0000x reference)
//
#include <hip/hip_runtime.h>

// SNN forward: 2-neuron, 2-layer LIF over T timesteps, batch-parallel.
//
// Round 3 structure: STREAM-SPECIALIZED ROLE SPLIT.
//   role = blockIdx.x % 3 -> 0: writes spk1, 1: writes spk2, 2: writes mem2.
// Roles 1/2 redundantly recompute the (cheap, ~100 VALU/iter) recurrence.
// Rationale: the monolithic kernel ran at ~141 us (~2.7 TB/s effective) while
// the harness's own fills prove 6.2 TB/s plain-store write BW. With 3908
// waves (15/CU) and 3 interleaved output streams per wave, store drain was
// latency/in-flight limited. This version: 3x waves (45/CU queued), one
// sequential stream per wave, 1 store/iter.
//
// NOTE on numerics: spikes are Heaviside outputs -> any ulp difference near
// the threshold flips 0<->1 (absmax 1.0). We disable FP contraction and
// mirror the reference's fp32 expression ordering exactly (identical
// expression trees in every role).

typedef float floatv4 __attribute__((ext_vector_type(4)));  // native clang vec

__global__ __launch_bounds__(256) void snn_fwd_kernel(
    const float* __restrict__ x,      // [B,2]
    const float* __restrict__ fc1_w,  // [2,2] row-major
    const float* __restrict__ fc1_b,  // [2]
    const float* __restrict__ beta1,  // [1]
    const float* __restrict__ thr1,   // [1]
    const float* __restrict__ fc2_w,  // [2,2]
    const float* __restrict__ fc2_b,  // [2]
    const float* __restrict__ beta2,  // [1]
    const float* __restrict__ thr2,   // [1]
    float* __restrict__ out,          // [3, T, B, 2] concatenated
    int B2, int T)                    // B2 = B/2 (pairs), B = 2*B2
{
#pragma clang fp contract(off)
    const int bid  = blockIdx.x;
    const int role = bid % 3;                       // 0: spk1, 1: spk2, 2: mem2
    const int tid  = (bid / 3) * blockDim.x + threadIdx.x;
    if (tid >= B2) return;

    // Two batch elements: (xv.x,xv.y) = elem a, (xv.z,xv.w) = elem b. 16B load.
    const floatv4 xv = ((const floatv4*)x)[tid];

    const float w00 = fc1_w[0], w01 = fc1_w[1], w10 = fc1_w[2], w11 = fc1_w[3];
    // cur1 = x @ fc1_w.T + fc1_b (constant over time; order: x0*w + x1*w, then +bias)
    const float ca0 = (xv.x * w00 + xv.y * w01) + fc1_b[0];
    const float ca1 = (xv.x * w10 + xv.y * w11) + fc1_b[1];
    const float cb0 = (xv.z * w00 + xv.w * w01) + fc1_b[0];
    const float cb1 = (xv.z * w10 + xv.w * w11) + fc1_b[1];

    const float b1 = fminf(fmaxf(beta1[0], 0.0f), 1.0f);
    const float t1 = thr1[0];

    // Layer-1 state (all roles need it).
    float m1a0 = 0.f, m1a1 = 0.f, m1b0 = 0.f, m1b1 = 0.f;

    const size_t TB2 = (size_t)T * (size_t)B2;       // float4s per stream
    size_t off = (size_t)tid;

    if (role == 0) {
        // ---- spk1 writer: layer-1 recurrence only ----
        floatv4* __restrict__ o = (floatv4*)out;
        for (int t = 0; t < T; ++t, off += (size_t)B2) {
            const float r1a0 = ((m1a0 - t1) > 0.f) ? 1.f : 0.f;
            const float r1a1 = ((m1a1 - t1) > 0.f) ? 1.f : 0.f;
            const float r1b0 = ((m1b0 - t1) > 0.f) ? 1.f : 0.f;
            const float r1b1 = ((m1b1 - t1) > 0.f) ? 1.f : 0.f;
            m1a0 = (b1 * m1a0 + ca0) - r1a0 * t1;
            m1a1 = (b1 * m1a1 + ca1) - r1a1 * t1;
            m1b0 = (b1 * m1b0 + cb0) - r1b0 * t1;
            m1b1 = (b1 * m1b1 + cb1) - r1b1 * t1;
            const float s1a0 = ((m1a0 - t1) > 0.f) ? 1.f : 0.f;
            const float s1a1 = ((m1a1 - t1) > 0.f) ? 1.f : 0.f;
            const float s1b0 = ((m1b0 - t1) > 0.f) ? 1.f : 0.f;
            const float s1b1 = ((m1b1 - t1) > 0.f) ? 1.f : 0.f;
            floatv4 o1; o1.x = s1a0; o1.y = s1a1; o1.z = s1b0; o1.w = s1b1;
            o[off] = o1;
        }
        return;
    }

    // ---- roles 1/2: full two-layer recurrence ----
    const float b2 = fminf(fmaxf(beta2[0], 0.0f), 1.0f);
    const float t2 = thr2[0];
    const float v00 = fc2_w[0], v01 = fc2_w[1], v10 = fc2_w[2], v11 = fc2_w[3];
    const float fb0 = fc2_b[0], fb1 = fc2_b[1];

    float m2a0 = 0.f, m2a1 = 0.f, m2b0 = 0.f, m2b1 = 0.f;

    floatv4* __restrict__ o = (role == 1) ? ((floatv4*)out + TB2)
                                          : ((floatv4*)out + 2 * TB2);
    const bool store_spk = (role == 1);

    for (int t = 0; t < T; ++t, off += (size_t)B2) {
        // --- layer 1 ---
        const float r1a0 = ((m1a0 - t1) > 0.f) ? 1.f : 0.f;
        const float r1a1 = ((m1a1 - t1) > 0.f) ? 1.f : 0.f;
        const float r1b0 = ((m1b0 - t1) > 0.f) ? 1.f : 0.f;
        const float r1b1 = ((m1b1 - t1) > 0.f) ? 1.f : 0.f;
        m1a0 = (b1 * m1a0 + ca0) - r1a0 * t1;
        m1a1 = (b1 * m1a1 + ca1) - r1a1 * t1;
        m1b0 = (b1 * m1b0 + cb0) - r1b0 * t1;
        m1b1 = (b1 * m1b1 + cb1) - r1b1 * t1;
        const float s1a0 = ((m1a0 - t1) > 0.f) ? 1.f : 0.f;
        const float s1a1 = ((m1a1 - t1) > 0.f) ? 1.f : 0.f;
        const float s1b0 = ((m1b0 - t1) > 0.f) ? 1.f : 0.f;
        const float s1b1 = ((m1b1 - t1) > 0.f) ? 1.f : 0.f;
        // --- layer 2 input ---
        const float c2a0 = (s1a0 * v00 + s1a1 * v01) + fb0;
        const float c2a1 = (s1a0 * v10 + s1a1 * v11) + fb1;
        const float c2b0 = (s1b0 * v00 + s1b1 * v01) + fb0;
        const float c2b1 = (s1b0 * v10 + s1b1 * v11) + fb1;
        // --- layer 2 ---
        const float r2a0 = ((m2a0 - t2) > 0.f) ? 1.f : 0.f;
        const float r2a1 = ((m2a1 - t2) > 0.f) ? 1.f : 0.f;
        const float r2b0 = ((m2b0 - t2) > 0.f) ? 1.f : 0.f;
        const float r2b1 = ((m2b1 - t2) > 0.f) ? 1.f : 0.f;
        m2a0 = (b2 * m2a0 + c2a0) - r2a0 * t2;
        m2a1 = (b2 * m2a1 + c2a1) - r2a1 * t2;
        m2b0 = (b2 * m2b0 + c2b0) - r2b0 * t2;
        m2b1 = (b2 * m2b1 + c2b1) - r2b1 * t2;

        floatv4 ov;
        if (store_spk) {
            ov.x = ((m2a0 - t2) > 0.f) ? 1.f : 0.f;
            ov.y = ((m2a1 - t2) > 0.f) ? 1.f : 0.f;
            ov.z = ((m2b0 - t2) > 0.f) ? 1.f : 0.f;
            ov.w = ((m2b1 - t2) > 0.f) ? 1.f : 0.f;
        } else {
            ov.x = m2a0; ov.y = m2a1; ov.z = m2b0; ov.w = m2b1;
        }
        o[off] = ov;
    }
}

extern "C" void kernel_launch(void* const* d_in, const int* in_sizes, int n_in,
                              void* d_out, int out_size, void* d_ws, size_t ws_size,
                              hipStream_t stream) {
    const float* x      = (const float*)d_in[0];
    const float* fc1_w  = (const float*)d_in[1];
    const float* fc1_b  = (const float*)d_in[2];
    const float* beta1  = (const float*)d_in[3];
    const float* thr1   = (const float*)d_in[4];
    const float* fc2_w  = (const float*)d_in[5];
    const float* fc2_b  = (const float*)d_in[6];
    const float* beta2  = (const float*)d_in[7];
    const float* thr2   = (const float*)d_in[8];
    float* out = (float*)d_out;

    const int B  = in_sizes[0] / 2;           // x is [B,2]; B = 500000 (even)
    const int T  = out_size / (6 * B);        // out = 3 streams * T * B * 2
    const int B2 = B / 2;                     // pairs per thread

    const int block = 256;
    const int blocksPerRole = (B2 + block - 1) / block;
    const int grid = 3 * blocksPerRole;       // roles interleaved: bid % 3
    snn_fwd_kernel<<<grid, block, 0, stream>>>(x, fc1_w, fc1_b, beta1, thr1,
                                               fc2_w, fc2_b, beta2, thr2,
                                               out, B2, T);
}

// Round 4
// 394.981 us; speedup vs baseline: 1.0104x; 1.0104x over previous
//
#include <hip/hip_runtime.h>

// SNN forward: 2-neuron, 2-layer LIF over T timesteps, batch-parallel.
//
// Round 4 structure: FILL-LIKE STORE STREAM.
// Each lane owns PAIRS=4 batch pairs, block-strided by 64 lanes, so per
// (stream, t) a wave issues 4 back-to-back 1KB stores = one 4KB sequential
// run (stream-major: 3 runs of 4KB per t). This mimics the harness fill
// kernel's per-wave sequential store bursts (6.2 TB/s at ~10% occupancy)
// instead of the previous 1KB-chunk-then-4MB-jump pattern (~2.8 TB/s eff).
// Grid: ~245 WGs (~1/CU) -- fills prove low occupancy saturates write BW.
//
// Prior A/Bs on this problem: nontemporal vs plain stores = null;
// 3x waves / stream-per-wave role split = -8 us. Store pattern is the
// remaining suspect.
//
// NOTE on numerics: spikes are Heaviside outputs -> any ulp difference near
// the threshold flips 0<->1 (absmax 1.0). We disable FP contraction and
// mirror the reference's fp32 expression ordering exactly (identical
// expression tree per batch element; only the batch->thread mapping changed).

typedef float floatv4 __attribute__((ext_vector_type(4)));  // native clang vec

#define PAIRS 4  // batch pairs per lane, strided by 64 lanes within a wave tile

__global__ __launch_bounds__(256) void snn_fwd_kernel(
    const float* __restrict__ x,      // [B,2]
    const float* __restrict__ fc1_w,  // [2,2] row-major
    const float* __restrict__ fc1_b,  // [2]
    const float* __restrict__ beta1,  // [1]
    const float* __restrict__ thr1,   // [1]
    const float* __restrict__ fc2_w,  // [2,2]
    const float* __restrict__ fc2_b,  // [2]
    const float* __restrict__ beta2,  // [1]
    const float* __restrict__ thr2,   // [1]
    float* __restrict__ out,          // [3, T, B, 2] concatenated
    int B2, int T)                    // B2 = B/2 (pairs), B = 2*B2
{
#pragma clang fp contract(off)
    const int lane  = threadIdx.x & 63;
    const int wv    = threadIdx.x >> 6;               // wave index in block (0..3)
    const int gwave = blockIdx.x * (blockDim.x >> 6) + wv;
    const int base  = gwave * (64 * PAIRS) + lane;    // wave tile = 256 pairs

    // Pair indices owned by this lane: base + j*64  (j = 0..PAIRS-1).
    int   p[PAIRS];
    bool  ok[PAIRS];
#pragma unroll
    for (int j = 0; j < PAIRS; ++j) { p[j] = base + j * 64; ok[j] = (p[j] < B2); }

    const float w00 = fc1_w[0], w01 = fc1_w[1], w10 = fc1_w[2], w11 = fc1_w[3];
    const float b1 = fminf(fmaxf(beta1[0], 0.0f), 1.0f);
    const float b2 = fminf(fmaxf(beta2[0], 0.0f), 1.0f);
    const float t1 = thr1[0];
    const float t2 = thr2[0];
    const float v00 = fc2_w[0], v01 = fc2_w[1], v10 = fc2_w[2], v11 = fc2_w[3];
    const float fb0 = fc2_b[0], fb1 = fc2_b[1];
    const float bi0 = fc1_b[0], bi1 = fc1_b[1];

    // cur1 per pair (constant over time; order: x0*w + x1*w, then +bias).
    float ca0[PAIRS], ca1[PAIRS], cb0[PAIRS], cb1[PAIRS];
#pragma unroll
    for (int j = 0; j < PAIRS; ++j) {
        floatv4 xv = {0.f, 0.f, 0.f, 0.f};
        if (ok[j]) xv = ((const floatv4*)x)[p[j]];
        ca0[j] = (xv.x * w00 + xv.y * w01) + bi0;
        ca1[j] = (xv.x * w10 + xv.y * w11) + bi1;
        cb0[j] = (xv.z * w00 + xv.w * w01) + bi0;
        cb1[j] = (xv.z * w10 + xv.w * w11) + bi1;
    }

    // State per pair.
    float m1a0[PAIRS], m1a1[PAIRS], m1b0[PAIRS], m1b1[PAIRS];
    float m2a0[PAIRS], m2a1[PAIRS], m2b0[PAIRS], m2b1[PAIRS];
#pragma unroll
    for (int j = 0; j < PAIRS; ++j) {
        m1a0[j] = m1a1[j] = m1b0[j] = m1b1[j] = 0.f;
        m2a0[j] = m2a1[j] = m2b0[j] = m2b1[j] = 0.f;
    }

    const size_t TB2 = (size_t)T * (size_t)B2;       // float4s per stream
    floatv4* __restrict__ spk1_out = (floatv4*)out;
    floatv4* __restrict__ spk2_out = (floatv4*)out + TB2;
    floatv4* __restrict__ mem2_out = (floatv4*)out + 2 * TB2;

    size_t trow = 0;                                  // t * B2
    for (int t = 0; t < T; ++t, trow += (size_t)B2) {
        floatv4 o1[PAIRS], o2[PAIRS], o3[PAIRS];
#pragma unroll
        for (int j = 0; j < PAIRS; ++j) {
            // --- layer 1 ---
            const float r1a0 = ((m1a0[j] - t1) > 0.f) ? 1.f : 0.f;
            const float r1a1 = ((m1a1[j] - t1) > 0.f) ? 1.f : 0.f;
            const float r1b0 = ((m1b0[j] - t1) > 0.f) ? 1.f : 0.f;
            const float r1b1 = ((m1b1[j] - t1) > 0.f) ? 1.f : 0.f;
            m1a0[j] = (b1 * m1a0[j] + ca0[j]) - r1a0 * t1;
            m1a1[j] = (b1 * m1a1[j] + ca1[j]) - r1a1 * t1;
            m1b0[j] = (b1 * m1b0[j] + cb0[j]) - r1b0 * t1;
            m1b1[j] = (b1 * m1b1[j] + cb1[j]) - r1b1 * t1;
            const float s1a0 = ((m1a0[j] - t1) > 0.f) ? 1.f : 0.f;
            const float s1a1 = ((m1a1[j] - t1) > 0.f) ? 1.f : 0.f;
            const float s1b0 = ((m1b0[j] - t1) > 0.f) ? 1.f : 0.f;
            const float s1b1 = ((m1b1[j] - t1) > 0.f) ? 1.f : 0.f;
            // --- layer 2 input ---
            const float c2a0 = (s1a0 * v00 + s1a1 * v01) + fb0;
            const float c2a1 = (s1a0 * v10 + s1a1 * v11) + fb1;
            const float c2b0 = (s1b0 * v00 + s1b1 * v01) + fb0;
            const float c2b1 = (s1b0 * v10 + s1b1 * v11) + fb1;
            // --- layer 2 ---
            const float r2a0 = ((m2a0[j] - t2) > 0.f) ? 1.f : 0.f;
            const float r2a1 = ((m2a1[j] - t2) > 0.f) ? 1.f : 0.f;
            const float r2b0 = ((m2b0[j] - t2) > 0.f) ? 1.f : 0.f;
            const float r2b1 = ((m2b1[j] - t2) > 0.f) ? 1.f : 0.f;
            m2a0[j] = (b2 * m2a0[j] + c2a0) - r2a0 * t2;
            m2a1[j] = (b2 * m2a1[j] + c2a1) - r2a1 * t2;
            m2b0[j] = (b2 * m2b0[j] + c2b0) - r2b0 * t2;
            m2b1[j] = (b2 * m2b1[j] + c2b1) - r2b1 * t2;
            const float s2a0 = ((m2a0[j] - t2) > 0.f) ? 1.f : 0.f;
            const float s2a1 = ((m2a1[j] - t2) > 0.f) ? 1.f : 0.f;
            const float s2b0 = ((m2b0[j] - t2) > 0.f) ? 1.f : 0.f;
            const float s2b1 = ((m2b1[j] - t2) > 0.f) ? 1.f : 0.f;

            o1[j].x = s1a0; o1[j].y = s1a1; o1[j].z = s1b0; o1[j].w = s1b1;
            o2[j].x = s2a0; o2[j].y = s2a1; o2[j].z = s2b0; o2[j].w = s2b1;
            o3[j].x = m2a0[j]; o3[j].y = m2a1[j]; o3[j].z = m2b0[j]; o3[j].w = m2b1[j];
        }
        // Stream-major store bursts: per stream, PAIRS back-to-back 1KB
        // wave-stores at consecutive addresses (one 4KB sequential run).
#pragma unroll
        for (int j = 0; j < PAIRS; ++j)
            if (ok[j]) spk1_out[trow + (size_t)p[j]] = o1[j];
#pragma unroll
        for (int j = 0; j < PAIRS; ++j)
            if (ok[j]) spk2_out[trow + (size_t)p[j]] = o2[j];
#pragma unroll
        for (int j = 0; j < PAIRS; ++j)
            if (ok[j]) mem2_out[trow + (size_t)p[j]] = o3[j];
    }
}

extern "C" void kernel_launch(void* const* d_in, const int* in_sizes, int n_in,
                              void* d_out, int out_size, void* d_ws, size_t ws_size,
                              hipStream_t stream) {
    const float* x      = (const float*)d_in[0];
    const float* fc1_w  = (const float*)d_in[1];
    const float* fc1_b  = (const float*)d_in[2];
    const float* beta1  = (const float*)d_in[3];
    const float* thr1   = (const float*)d_in[4];
    const float* fc2_w  = (const float*)d_in[5];
    const float* fc2_b  = (const float*)d_in[6];
    const float* beta2  = (const float*)d_in[7];
    const float* thr2   = (const float*)d_in[8];
    float* out = (float*)d_out;

    const int B  = in_sizes[0] / 2;           // x is [B,2]; B = 500000 (even)
    const int T  = out_size / (6 * B);        // out = 3 streams * T * B * 2
    const int B2 = B / 2;                     // pairs per thread-slot

    const int block = 256;                    // 4 waves; wave tile = 256 pairs
    const int pairsPerBlock = block * PAIRS;  // 1024 pairs
    const int grid = (B2 + pairsPerBlock - 1) / pairsPerBlock;  // ~245 WGs
    snn_fwd_kernel<<<grid, block, 0, stream>>>(x, fc1_w, fc1_b, beta1, thr1,
                                               fc2_w, fc2_b, beta2, thr2,
                                               out, B2, T);
}

// Round 5
// 393.676 us; speedup vs baseline: 1.0138x; 1.0033x over previous
//
#include <hip/hip_runtime.h>

// SNN forward: 2-neuron, 2-layer LIF over T timesteps, batch-parallel.
// Two batch elements per thread -> all output stores are 16 B/lane
// (global_store_dwordx4), plain (non-nt) stores.
//
// FINAL STRUCTURE (best measured: 391.6 us). Session A/B history:
//   - nontemporal vs plain stores: null (392.8 vs 391.6)
//   - 3x-wave stream-role split:   -7.5 us (issue overhead visible)
//   - 4KB fill-like store bursts:  -3.4 us (occupancy drop visible)
// Conclusion: kernel is at its write floor (~62-80 us for the compulsory
// 384 MB at ~6.2 TB/s achievable). The measured dur_us (~392) is dominated
// by the harness's per-iteration 1.536 GB poison fill (~250 us, visible in
// every rocprof top-5) plus reset/restore slop -- not by this kernel.
//
// NOTE on numerics: spikes are Heaviside outputs -> any ulp difference near
// the threshold flips 0<->1 (absmax 1.0). We disable FP contraction and
// mirror the reference's fp32 expression ordering exactly.

typedef float floatv4 __attribute__((ext_vector_type(4)));  // native clang vec

__global__ __launch_bounds__(256) void snn_fwd_kernel(
    const float* __restrict__ x,      // [B,2]
    const float* __restrict__ fc1_w,  // [2,2] row-major
    const float* __restrict__ fc1_b,  // [2]
    const float* __restrict__ beta1,  // [1]
    const float* __restrict__ thr1,   // [1]
    const float* __restrict__ fc2_w,  // [2,2]
    const float* __restrict__ fc2_b,  // [2]
    const float* __restrict__ beta2,  // [1]
    const float* __restrict__ thr2,   // [1]
    float* __restrict__ out,          // [3, T, B, 2] concatenated
    int B2, int T)                    // B2 = B/2 (pairs), B = 2*B2
{
#pragma clang fp contract(off)
    int tid = blockIdx.x * blockDim.x + threadIdx.x;
    if (tid >= B2) return;

    // Two batch elements: (xv.x,xv.y) = elem a, (xv.z,xv.w) = elem b. 16B load.
    const floatv4 xv = ((const floatv4*)x)[tid];

    const float w00 = fc1_w[0], w01 = fc1_w[1], w10 = fc1_w[2], w11 = fc1_w[3];
    // cur1 = x @ fc1_w.T + fc1_b (constant over time; order: x0*w + x1*w, then +bias)
    const float ca0 = (xv.x * w00 + xv.y * w01) + fc1_b[0];
    const float ca1 = (xv.x * w10 + xv.y * w11) + fc1_b[1];
    const float cb0 = (xv.z * w00 + xv.w * w01) + fc1_b[0];
    const float cb1 = (xv.z * w10 + xv.w * w11) + fc1_b[1];

    const float b1 = fminf(fmaxf(beta1[0], 0.0f), 1.0f);
    const float b2 = fminf(fmaxf(beta2[0], 0.0f), 1.0f);
    const float t1 = thr1[0];
    const float t2 = thr2[0];

    const float v00 = fc2_w[0], v01 = fc2_w[1], v10 = fc2_w[2], v11 = fc2_w[3];
    const float fb0 = fc2_b[0], fb1 = fc2_b[1];

    // State for both elements.
    float m1a0 = 0.f, m1a1 = 0.f, m1b0 = 0.f, m1b1 = 0.f;
    float m2a0 = 0.f, m2a1 = 0.f, m2b0 = 0.f, m2b1 = 0.f;

    const size_t TB2 = (size_t)T * (size_t)B2;       // float4s per stream
    floatv4* __restrict__ spk1_out = (floatv4*)out;
    floatv4* __restrict__ spk2_out = (floatv4*)out + TB2;
    floatv4* __restrict__ mem2_out = (floatv4*)out + 2 * TB2;

    size_t off = (size_t)tid;
    for (int t = 0; t < T; ++t, off += (size_t)B2) {
        // --- layer 1 ---
        const float r1a0 = ((m1a0 - t1) > 0.f) ? 1.f : 0.f;
        const float r1a1 = ((m1a1 - t1) > 0.f) ? 1.f : 0.f;
        const float r1b0 = ((m1b0 - t1) > 0.f) ? 1.f : 0.f;
        const float r1b1 = ((m1b1 - t1) > 0.f) ? 1.f : 0.f;
        m1a0 = (b1 * m1a0 + ca0) - r1a0 * t1;
        m1a1 = (b1 * m1a1 + ca1) - r1a1 * t1;
        m1b0 = (b1 * m1b0 + cb0) - r1b0 * t1;
        m1b1 = (b1 * m1b1 + cb1) - r1b1 * t1;
        const float s1a0 = ((m1a0 - t1) > 0.f) ? 1.f : 0.f;
        const float s1a1 = ((m1a1 - t1) > 0.f) ? 1.f : 0.f;
        const float s1b0 = ((m1b0 - t1) > 0.f) ? 1.f : 0.f;
        const float s1b1 = ((m1b1 - t1) > 0.f) ? 1.f : 0.f;
        // --- layer 2 input ---
        const float c2a0 = (s1a0 * v00 + s1a1 * v01) + fb0;
        const float c2a1 = (s1a0 * v10 + s1a1 * v11) + fb1;
        const float c2b0 = (s1b0 * v00 + s1b1 * v01) + fb0;
        const float c2b1 = (s1b0 * v10 + s1b1 * v11) + fb1;
        // --- layer 2 ---
        const float r2a0 = ((m2a0 - t2) > 0.f) ? 1.f : 0.f;
        const float r2a1 = ((m2a1 - t2) > 0.f) ? 1.f : 0.f;
        const float r2b0 = ((m2b0 - t2) > 0.f) ? 1.f : 0.f;
        const float r2b1 = ((m2b1 - t2) > 0.f) ? 1.f : 0.f;
        m2a0 = (b2 * m2a0 + c2a0) - r2a0 * t2;
        m2a1 = (b2 * m2a1 + c2a1) - r2a1 * t2;
        m2b0 = (b2 * m2b0 + c2b0) - r2b0 * t2;
        m2b1 = (b2 * m2b1 + c2b1) - r2b1 * t2;
        const float s2a0 = ((m2a0 - t2) > 0.f) ? 1.f : 0.f;
        const float s2a1 = ((m2a1 - t2) > 0.f) ? 1.f : 0.f;
        const float s2b0 = ((m2b0 - t2) > 0.f) ? 1.f : 0.f;
        const float s2b1 = ((m2b1 - t2) > 0.f) ? 1.f : 0.f;

        floatv4 o1; o1.x = s1a0; o1.y = s1a1; o1.z = s1b0; o1.w = s1b1;
        floatv4 o2; o2.x = s2a0; o2.y = s2a1; o2.z = s2b0; o2.w = s2b1;
        floatv4 o3; o3.x = m2a0; o3.y = m2a1; o3.z = m2b0; o3.w = m2b1;
        spk1_out[off] = o1;
        spk2_out[off] = o2;
        mem2_out[off] = o3;
    }
}

extern "C" void kernel_launch(void* const* d_in, const int* in_sizes, int n_in,
                              void* d_out, int out_size, void* d_ws, size_t ws_size,
                              hipStream_t stream) {
    const float* x      = (const float*)d_in[0];
    const float* fc1_w  = (const float*)d_in[1];
    const float* fc1_b  = (const float*)d_in[2];
    const float* beta1  = (const float*)d_in[3];
    const float* thr1   = (const float*)d_in[4];
    const float* fc2_w  = (const float*)d_in[5];
    const float* fc2_b  = (const float*)d_in[6];
    const float* beta2  = (const float*)d_in[7];
    const float* thr2   = (const float*)d_in[8];
    float* out = (float*)d_out;

    const int B  = in_sizes[0] / 2;           // x is [B,2]; B = 500000 (even)
    const int T  = out_size / (6 * B);        // out = 3 streams * T * B * 2
    const int B2 = B / 2;                     // pairs per thread

    const int block = 256;
    const int grid = (B2 + block - 1) / block;
    snn_fwd_kernel<<<grid, block, 0, stream>>>(x, fc1_w, fc1_b, beta1, thr1,
                                               fc2_w, fc2_b, beta2, thr2,
                                               out, B2, T);
}